// Round 5
// baseline (428.335 us; speedup 1.0000x reference)
//
#include <hip/hip_runtime.h>
#include <hip/hip_bf16.h>
#include <math.h>

#define F 128

static __device__ __forceinline__ unsigned short f2bf(float f) {
  unsigned u = __float_as_uint(f);
  unsigned r = (u + 0x7fffu + ((u >> 16) & 1u)) >> 16;  // RTN-even
  return (unsigned short)r;
}

// ---------------- utility: zero int buffer ---------------------------------
__global__ __launch_bounds__(256) void zero_kernel(int* __restrict__ p, int n) {
  int i = blockIdx.x * 256 + threadIdx.x;
  if (i < n) p[i] = 0;
}

// ---------------- GEMM body (32 node rows per block) ------------------------
// writes A_in (f32, +b_att) and packed P row per node:
//   P[n][0..127]=bf16(A_out), P[n][128..255]=bf16(WN=+b_lin)
static __device__ void gemm_body(
    int blockRow, const float* __restrict__ node,
    const float* __restrict__ W_lin, const float* __restrict__ b_lin,
    const float* __restrict__ W_att, const float* __restrict__ b_att,
    float* __restrict__ A_in, unsigned short* __restrict__ P, int nNodes) {
  __shared__ float xs[32][F];
  const int t = threadIdx.x;

  for (int i = t; i < 32 * 32; i += 256) {  // 1024 float4s
    int r = i >> 5, c4 = i & 31;
    int gr = blockRow + r;
    float4 v = (gr < nNodes) ? ((const float4*)node)[(size_t)gr * 32 + c4]
                             : float4{0.f, 0.f, 0.f, 0.f};
    *(float4*)&xs[r][c4 * 4] = v;
  }
  __syncthreads();

  const int c0 = (t & 63) * 2;
  const int rg = t >> 6;

  float a0[8][2], a1[8][2], a2[8][2];
#pragma unroll
  for (int r = 0; r < 8; ++r)
    a0[r][0] = a0[r][1] = a1[r][0] = a1[r][1] = a2[r][0] = a2[r][1] = 0.f;

  for (int k0 = 0; k0 < F; k0 += 4) {
    float2 w0[4], w1[4], w2[4];
#pragma unroll
    for (int j = 0; j < 4; ++j) {
      w0[j] = *(const float2*)&W_att[(k0 + j) * F + c0];
      w1[j] = *(const float2*)&W_att[(k0 + j + F) * F + c0];
      w2[j] = *(const float2*)&W_lin[(k0 + j) * F + c0];
    }
#pragma unroll
    for (int r = 0; r < 8; ++r) {
      const float4 x = *(const float4*)&xs[rg * 8 + r][k0];
      const float xv[4] = {x.x, x.y, x.z, x.w};
#pragma unroll
      for (int j = 0; j < 4; ++j) {
        a0[r][0] = fmaf(xv[j], w0[j].x, a0[r][0]);
        a0[r][1] = fmaf(xv[j], w0[j].y, a0[r][1]);
        a1[r][0] = fmaf(xv[j], w1[j].x, a1[r][0]);
        a1[r][1] = fmaf(xv[j], w1[j].y, a1[r][1]);
        a2[r][0] = fmaf(xv[j], w2[j].x, a2[r][0]);
        a2[r][1] = fmaf(xv[j], w2[j].y, a2[r][1]);
      }
    }
  }

  const float2 ba = *(const float2*)&b_att[c0];
  const float2 bl = *(const float2*)&b_lin[c0];
#pragma unroll
  for (int r = 0; r < 8; ++r) {
    int gr = blockRow + rg * 8 + r;
    if (gr < nNodes) {
      float2 va = {a0[r][0] + ba.x, a0[r][1] + ba.y};
      *(float2*)&A_in[(size_t)gr * F + c0] = va;
      ushort2 po = {f2bf(a1[r][0]), f2bf(a1[r][1])};
      *(ushort2*)&P[(size_t)gr * 256 + c0] = po;
      ushort2 pw = {f2bf(a2[r][0] + bl.x), f2bf(a2[r][1] + bl.y)};
      *(ushort2*)&P[(size_t)gr * 256 + 128 + c0] = pw;
    }
  }
}

// ---------------- K1: degree (grid-stride) || GEMM first half ---------------
__global__ __launch_bounds__(256) void k1_degree_gemm(
    const int2* __restrict__ ei2, int* __restrict__ deg, int nEdges, int DB,
    const float* __restrict__ node,
    const float* __restrict__ W_lin, const float* __restrict__ b_lin,
    const float* __restrict__ W_att, const float* __restrict__ b_att,
    float* __restrict__ A_in, unsigned short* __restrict__ P, int nNodes) {
  if ((int)blockIdx.x < DB) {
    for (int e = blockIdx.x * 256 + threadIdx.x; e < nEdges; e += DB * 256)
      atomicAdd(&deg[ei2[e].x], 1);
    return;
  }
  gemm_body((blockIdx.x - DB) * 32, node, W_lin, b_lin, W_att, b_att,
            A_in, P, nNodes);
}

// ---------------- scan stages ----------------------------------------------
__global__ __launch_bounds__(256) void scan_a(
    const int* __restrict__ deg, int* __restrict__ rs, int* __restrict__ bsum,
    int n) {
  __shared__ int sdata[256];
  const int b = blockIdx.x, t = threadIdx.x;
  const int base = b * 1024 + t * 4;
  int v[4], s = 0;
#pragma unroll
  for (int j = 0; j < 4; ++j) {
    v[j] = (base + j < n) ? deg[base + j] : 0;
    s += v[j];
  }
  sdata[t] = s;
  __syncthreads();
  for (int off = 1; off < 256; off <<= 1) {
    int x = (t >= off) ? sdata[t - off] : 0;
    __syncthreads();
    sdata[t] += x;
    __syncthreads();
  }
  int ex = sdata[t] - s;
#pragma unroll
  for (int j = 0; j < 4; ++j) {
    if (base + j < n) rs[base + j] = ex;
    ex += v[j];
  }
  if (t == 255) bsum[b] = sdata[255];
}

__global__ void scan_b(int* __restrict__ bsum, int nb) {
  const int lane = threadIdx.x;  // 64 threads, 1 block
  if (nb <= 64) {
    int v = (lane < nb) ? bsum[lane] : 0;
    const int orig = v;
    for (int off = 1; off < 64; off <<= 1) {
      int u = __shfl_up(v, off);
      if (lane >= off) v += u;
    }
    if (lane < nb) bsum[lane] = v - orig;  // exclusive
  } else if (lane == 0) {
    int run = 0;
    for (int i = 0; i < nb; ++i) { int t = bsum[i]; bsum[i] = run; run += t; }
  }
}

__global__ __launch_bounds__(256) void scan_c(
    int* __restrict__ rs, const int* __restrict__ bsum, int* __restrict__ fill,
    int n, int nEdges) {
  int i = blockIdx.x * 256 + threadIdx.x;
  if (i < n) {
    int v = rs[i] + bsum[i >> 10];
    rs[i] = v;
    fill[i] = v;
  }
  if (i == 0) rs[n] = nEdges;
}

// ---------------- K2: scatter || GEMM second half ---------------------------
__global__ __launch_bounds__(256) void k2_scatter_gemm(
    const int2* __restrict__ ei2, int* __restrict__ fill,
    int* __restrict__ sorted_send, int nEdges, int SB, int nodeLo,
    const float* __restrict__ node,
    const float* __restrict__ W_lin, const float* __restrict__ b_lin,
    const float* __restrict__ W_att, const float* __restrict__ b_att,
    float* __restrict__ A_in, unsigned short* __restrict__ P, int nNodes) {
  if ((int)blockIdx.x < SB) {
    int e = blockIdx.x * 256 + threadIdx.x;
    if (e < nEdges) {
      int2 p = ei2[e];
      int pos = atomicAdd(&fill[p.x], 1);
      sorted_send[pos] = p.y;
    }
    return;
  }
  gemm_body(nodeLo + (blockIdx.x - SB) * 32, node, W_lin, b_lin, W_att, b_att,
            A_in, P, nNodes);
}

// ---------------- Fused per-node: logits + softmax (no max) + aggregate -----
// 1 wave/node; 16-lane row groups: lane = (g<<4)|f, group g handles one edge
// per 4-edge step, lane reads P features 8f..8f+7 as ushort8 (16B).
// leaky(u) = 0.6u + 0.4|u|; abs is a free VOP3 modifier.
__global__ __launch_bounds__(256) void fused_node(
    const float* __restrict__ A_in, const unsigned short* __restrict__ P,
    const float* __restrict__ w_alpha,
    const int* __restrict__ row_start, const int* __restrict__ sorted_send,
    float* __restrict__ out, int nNodes) {
  const int node = blockIdx.x * 4 + (threadIdx.x >> 6);
  const int lane = threadIdx.x & 63;
  if (node >= nNodes) return;
  const int g = lane >> 4;
  const int f = lane & 15;
  const size_t no = (size_t)node * F;

  const float4 ai0 = *(const float4*)&A_in[no + (f << 3)];
  const float4 ai1 = *(const float4*)&A_in[no + (f << 3) + 4];
  const float4 wa0 = *(const float4*)&w_alpha[f << 3];
  const float4 wa1 = *(const float4*)&w_alpha[(f << 3) + 4];

  const char* Pb = (const char*)P + (f << 4);  // +f*16 bytes within row

  float acc[8] = {0.f, 0.f, 0.f, 0.f, 0.f, 0.f, 0.f, 0.f};
  float pacc = 0.f;

  const int e0 = row_start[node], e1 = row_start[node + 1];

  uint4 qa[4], wb[4];

#define ISSUE(S, ST)                                                  \
  {                                                                   \
    int srow = __shfl(myidx, ((ST) << 2) + g);                        \
    const uint4* rp = (const uint4*)(Pb + (size_t)srow * 512);        \
    qa[S] = rp[0];                                                    \
    wb[S] = rp[16];                                                   \
  }

#define UNPK(w, aL, aH, wL, wH)                                       \
  {                                                                   \
    float xl = __uint_as_float((w) << 16);                            \
    float xh = __uint_as_float((w) & 0xffff0000u);                    \
    float uL = xl + (aL), uH = xh + (aH);                             \
    ta = fmaf((wL), uL, ta); tb = fmaf((wL), fabsf(uL), tb);          \
    ta = fmaf((wH), uH, ta); tb = fmaf((wH), fabsf(uH), tb);          \
  }

#define PHB(w, k0, k1)                                                \
  {                                                                   \
    float xl = __uint_as_float((w) << 16);                            \
    float xh = __uint_as_float((w) & 0xffff0000u);                    \
    acc[k0] = fmaf(xl, p, acc[k0]);                                   \
    acc[k1] = fmaf(xh, p, acc[k1]);                                   \
  }

#define COMPUTE(S, ST)                                                \
  {                                                                   \
    float ta = 0.f, tb = 0.f;                                         \
    UNPK(qa[S].x, ai0.x, ai0.y, wa0.x, wa0.y);                        \
    UNPK(qa[S].y, ai0.z, ai0.w, wa0.z, wa0.w);                        \
    UNPK(qa[S].z, ai1.x, ai1.y, wa1.x, wa1.y);                        \
    UNPK(qa[S].w, ai1.z, ai1.w, wa1.z, wa1.w);                        \
    float t = fmaf(0.6f, ta, 0.4f * tb);                              \
    t += __shfl_xor(t, 1);                                            \
    t += __shfl_xor(t, 2);                                            \
    t += __shfl_xor(t, 4);                                            \
    t += __shfl_xor(t, 8);                                            \
    float p = (base + ((ST) << 2) + g < e1) ? __expf(t) : 0.f;        \
    pacc += p;                                                        \
    PHB(wb[S].x, 0, 1);                                               \
    PHB(wb[S].y, 2, 3);                                               \
    PHB(wb[S].z, 4, 5);                                               \
    PHB(wb[S].w, 6, 7);                                               \
  }

  for (int base = e0; base < e1; base += 64) {
    int myidx = (base + lane < e1) ? sorted_send[base + lane] : 0;
    const int rem = e1 - base;
    const int nst = ((rem < 64 ? rem : 64) + 3) >> 2;  // 4-edge steps

    if (nst > 0) ISSUE(0, 0);
    if (nst > 1) ISSUE(1, 1);
    if (nst > 2) ISSUE(2, 2);
    if (nst > 3) ISSUE(3, 3);

    int st = 0;
    for (; st + 4 <= nst; st += 4) {
      COMPUTE(0, st);
      if (st + 4 < nst) ISSUE(0, st + 4);
      COMPUTE(1, st + 1);
      if (st + 5 < nst) ISSUE(1, st + 5);
      COMPUTE(2, st + 2);
      if (st + 6 < nst) ISSUE(2, st + 6);
      COMPUTE(3, st + 3);
      if (st + 7 < nst) ISSUE(3, st + 7);
    }
    if (st < nst) COMPUTE(0, st);
    if (st + 1 < nst) COMPUTE(1, st + 1);
    if (st + 2 < nst) COMPUTE(2, st + 2);
  }

#undef ISSUE
#undef UNPK
#undef PHB
#undef COMPUTE

  // combine the 4 groups
#pragma unroll
  for (int k = 0; k < 8; ++k) {
    acc[k] += __shfl_xor(acc[k], 16);
    acc[k] += __shfl_xor(acc[k], 32);
  }
  pacc += __shfl_xor(pacc, 16);
  pacc += __shfl_xor(pacc, 32);

  const float inv = 1.f / fmaxf(pacc, 1e-12f);
  if (lane < 16) {
    float o[8];
#pragma unroll
    for (int k = 0; k < 8; ++k) {
      float v = acc[k] * inv;
      o[k] = (v > 0.f) ? v : expm1f(v);
    }
    *(float4*)&out[no + (f << 3)]     = float4{o[0], o[1], o[2], o[3]};
    *(float4*)&out[no + (f << 3) + 4] = float4{o[4], o[5], o[6], o[7]};
  }
}

extern "C" void kernel_launch(void* const* d_in, const int* in_sizes, int n_in,
                              void* d_out, int out_size, void* d_ws, size_t ws_size,
                              hipStream_t stream) {
  const float* node    = (const float*)d_in[0];
  // d_in[1] = edge features: UNUSED by the reference
  const int*   ei      = (const int*)d_in[2];
  const float* W_lin   = (const float*)d_in[3];
  const float* b_lin   = (const float*)d_in[4];
  const float* W_att   = (const float*)d_in[5];
  const float* b_att   = (const float*)d_in[6];
  const float* w_alpha = (const float*)d_in[7];

  const int nNodes = in_sizes[0] / F;
  const int nEdges = in_sizes[2] / 2;

  float* ws = (float*)d_ws;
  const size_t nf = (size_t)nNodes * F;
  float*          A_in = ws;                          // nf f32
  unsigned short* P    = (unsigned short*)(ws + nf);  // nNodes*256 bf16
  int* ibase       = (int*)(ws + 2 * nf);
  int* deg         = ibase;                        // nNodes
  int* row_start   = ibase + nNodes;               // nNodes + 1
  int* bsum        = ibase + 2 * nNodes + 1;       // 256
  int* fill        = ibase + 2 * nNodes + 257;     // nNodes
  int* sorted_send = ibase + 3 * nNodes + 257;     // nEdges

  const int nScanBlocks = (nNodes + 1023) / 1024;
  const int SB = (nEdges + 255) / 256;
  const int DB = 1024;
  const int nHalf = ((nNodes / 2) + 31) & ~31;
  const int G1 = nHalf / 32;
  const int G2 = (nNodes - nHalf + 31) / 32;

  zero_kernel<<<(nNodes + 255) / 256, 256, 0, stream>>>(deg, nNodes);
  k1_degree_gemm<<<DB + G1, 256, 0, stream>>>(
      (const int2*)ei, deg, nEdges, DB,
      node, W_lin, b_lin, W_att, b_att, A_in, P, nNodes);
  scan_a<<<nScanBlocks, 256, 0, stream>>>(deg, row_start, bsum, nNodes);
  scan_b<<<1, 64, 0, stream>>>(bsum, nScanBlocks);
  scan_c<<<(nNodes + 255) / 256, 256, 0, stream>>>(row_start, bsum, fill,
                                                   nNodes, nEdges);
  k2_scatter_gemm<<<SB + G2, 256, 0, stream>>>(
      (const int2*)ei, fill, sorted_send, nEdges, SB, nHalf,
      node, W_lin, b_lin, W_att, b_att, A_in, P, nNodes);

  fused_node<<<(nNodes + 3) / 4, 256, 0, stream>>>(
      A_in, P, w_alpha, row_start, sorted_send, (float*)d_out, nNodes);
}

// Round 6
// 411.258 us; speedup vs baseline: 1.0415x; 1.0415x over previous
//
#include <hip/hip_runtime.h>
#include <hip/hip_bf16.h>
#include <math.h>

#define F 128

static __device__ __forceinline__ unsigned short f2bf(float f) {
  unsigned u = __float_as_uint(f);
  unsigned r = (u + 0x7fffu + ((u >> 16) & 1u)) >> 16;  // RTN-even
  return (unsigned short)r;
}

// ---------------- utility: zero int buffer ---------------------------------
__global__ __launch_bounds__(256) void zero_kernel(int* __restrict__ p, int n) {
  int i = blockIdx.x * 256 + threadIdx.x;
  if (i < n) p[i] = 0;
}

// ---------------- CSR build ------------------------------------------------
__global__ __launch_bounds__(256) void degree_kernel(
    const int2* __restrict__ ei2, int* __restrict__ deg, int nEdges) {
  int e = blockIdx.x * 256 + threadIdx.x;
  if (e < nEdges) atomicAdd(&deg[ei2[e].x], 1);
}

__global__ __launch_bounds__(256) void scan_a(
    const int* __restrict__ deg, int* __restrict__ rs, int* __restrict__ bsum,
    int n) {
  __shared__ int sdata[256];
  const int b = blockIdx.x, t = threadIdx.x;
  const int base = b * 1024 + t * 4;
  int v[4], s = 0;
#pragma unroll
  for (int j = 0; j < 4; ++j) {
    v[j] = (base + j < n) ? deg[base + j] : 0;
    s += v[j];
  }
  sdata[t] = s;
  __syncthreads();
  for (int off = 1; off < 256; off <<= 1) {
    int x = (t >= off) ? sdata[t - off] : 0;
    __syncthreads();
    sdata[t] += x;
    __syncthreads();
  }
  int ex = sdata[t] - s;
#pragma unroll
  for (int j = 0; j < 4; ++j) {
    if (base + j < n) rs[base + j] = ex;
    ex += v[j];
  }
  if (t == 255) bsum[b] = sdata[255];
}

__global__ void scan_b(int* __restrict__ bsum, int nb) {
  const int lane = threadIdx.x;  // 64 threads, 1 block
  if (nb <= 64) {
    int v = (lane < nb) ? bsum[lane] : 0;
    const int orig = v;
    for (int off = 1; off < 64; off <<= 1) {
      int u = __shfl_up(v, off);
      if (lane >= off) v += u;
    }
    if (lane < nb) bsum[lane] = v - orig;  // exclusive
  } else if (lane == 0) {
    int run = 0;
    for (int i = 0; i < nb; ++i) { int t = bsum[i]; bsum[i] = run; run += t; }
  }
}

__global__ __launch_bounds__(256) void scan_c(
    int* __restrict__ rs, const int* __restrict__ bsum, int* __restrict__ fill,
    int n, int nEdges) {
  int i = blockIdx.x * 256 + threadIdx.x;
  if (i < n) {
    int v = rs[i] + bsum[i >> 10];
    rs[i] = v;
    fill[i] = v;
  }
  if (i == 0) rs[n] = nEdges;
}

// ---------------- GEMM body (32 node rows per block) ------------------------
static __device__ void gemm_body(
    int blockRow, const float* __restrict__ node,
    const float* __restrict__ W_lin, const float* __restrict__ b_lin,
    const float* __restrict__ W_att, const float* __restrict__ b_att,
    float* __restrict__ A_in, unsigned short* __restrict__ P, int nNodes) {
  __shared__ float xs[32][F];
  const int t = threadIdx.x;

  for (int i = t; i < 32 * 32; i += 256) {
    int r = i >> 5, c4 = i & 31;
    int gr = blockRow + r;
    float4 v = (gr < nNodes) ? ((const float4*)node)[(size_t)gr * 32 + c4]
                             : float4{0.f, 0.f, 0.f, 0.f};
    *(float4*)&xs[r][c4 * 4] = v;
  }
  __syncthreads();

  const int c0 = (t & 63) * 2;
  const int rg = t >> 6;

  float a0[8][2], a1[8][2], a2[8][2];
#pragma unroll
  for (int r = 0; r < 8; ++r)
    a0[r][0] = a0[r][1] = a1[r][0] = a1[r][1] = a2[r][0] = a2[r][1] = 0.f;

  for (int k0 = 0; k0 < F; k0 += 4) {
    float2 w0[4], w1[4], w2[4];
#pragma unroll
    for (int j = 0; j < 4; ++j) {
      w0[j] = *(const float2*)&W_att[(k0 + j) * F + c0];
      w1[j] = *(const float2*)&W_att[(k0 + j + F) * F + c0];
      w2[j] = *(const float2*)&W_lin[(k0 + j) * F + c0];
    }
#pragma unroll
    for (int r = 0; r < 8; ++r) {
      const float4 x = *(const float4*)&xs[rg * 8 + r][k0];
      const float xv[4] = {x.x, x.y, x.z, x.w};
#pragma unroll
      for (int j = 0; j < 4; ++j) {
        a0[r][0] = fmaf(xv[j], w0[j].x, a0[r][0]);
        a0[r][1] = fmaf(xv[j], w0[j].y, a0[r][1]);
        a1[r][0] = fmaf(xv[j], w1[j].x, a1[r][0]);
        a1[r][1] = fmaf(xv[j], w1[j].y, a1[r][1]);
        a2[r][0] = fmaf(xv[j], w2[j].x, a2[r][0]);
        a2[r][1] = fmaf(xv[j], w2[j].y, a2[r][1]);
      }
    }
  }

  const float2 ba = *(const float2*)&b_att[c0];
  const float2 bl = *(const float2*)&b_lin[c0];
#pragma unroll
  for (int r = 0; r < 8; ++r) {
    int gr = blockRow + rg * 8 + r;
    if (gr < nNodes) {
      float2 va = {a0[r][0] + ba.x, a0[r][1] + ba.y};
      *(float2*)&A_in[(size_t)gr * F + c0] = va;
      ushort2 po = {f2bf(a1[r][0]), f2bf(a1[r][1])};
      *(ushort2*)&P[(size_t)gr * 256 + c0] = po;
      ushort2 pw = {f2bf(a2[r][0] + bl.x), f2bf(a2[r][1] + bl.y)};
      *(ushort2*)&P[(size_t)gr * 256 + 128 + c0] = pw;
    }
  }
}

// ---------------- Combined: scatter (CSR fill)  ||  full GEMM ---------------
__global__ __launch_bounds__(256) void combo_kernel(
    const int2* __restrict__ ei2, int* __restrict__ fill,
    int* __restrict__ sorted_send, int nEdges, int SB,
    const float* __restrict__ node,
    const float* __restrict__ W_lin, const float* __restrict__ b_lin,
    const float* __restrict__ W_att, const float* __restrict__ b_att,
    float* __restrict__ A_in, unsigned short* __restrict__ P, int nNodes) {
  if ((int)blockIdx.x < SB) {
    int e = blockIdx.x * 256 + threadIdx.x;
    if (e < nEdges) {
      int2 p = ei2[e];
      int pos = atomicAdd(&fill[p.x], 1);
      sorted_send[pos] = p.y;
    }
    return;
  }
  gemm_body((blockIdx.x - SB) * 32, node, W_lin, b_lin, W_att, b_att,
            A_in, P, nNodes);
}

// ---------------- Pass A: logits -> p[edge], inv_denom[node] ---------------
// 1 wave/node; 16-lane groups (lane = g*16+f): group g handles one edge per
// 4-edge step; lane reads A_out features 8f..8f+7 as uint4 (16B).
// leaky(u) dot = 0.6*ta + 0.4*tb with ta=sum(w*u), tb=sum(w*|u|) (abs free).
__global__ __launch_bounds__(256) void logits_node(
    const float* __restrict__ A_in, const unsigned short* __restrict__ P,
    const float* __restrict__ w_alpha,
    const int* __restrict__ row_start, const int* __restrict__ sorted_send,
    float* __restrict__ p_out, float* __restrict__ inv_denom, int nNodes) {
  const int node = blockIdx.x * 4 + (threadIdx.x >> 6);
  const int lane = threadIdx.x & 63;
  if (node >= nNodes) return;
  const int g = lane >> 4;
  const int f = lane & 15;
  const size_t no = (size_t)node * F;

  const float4 ai0 = *(const float4*)&A_in[no + (f << 3)];
  const float4 ai1 = *(const float4*)&A_in[no + (f << 3) + 4];
  const float4 wa0 = *(const float4*)&w_alpha[f << 3];
  const float4 wa1 = *(const float4*)&w_alpha[(f << 3) + 4];

  const char* Pb = (const char*)P + (f << 4);  // bytes f*16 within A_out half

  float pacc = 0.f;
  const int e0 = row_start[node], e1 = row_start[node + 1];
  uint4 qa[4];

#define ISSUE_A(S, ST)                                                \
  {                                                                   \
    int srow = __shfl(myidx, ((ST) << 2) + g);                        \
    qa[S] = *(const uint4*)(Pb + (size_t)srow * 512);                 \
  }

#define UNPK(w, aL, aH, wL, wH)                                       \
  {                                                                   \
    float xl = __uint_as_float((w) << 16);                            \
    float xh = __uint_as_float((w) & 0xffff0000u);                    \
    float uL = xl + (aL), uH = xh + (aH);                             \
    ta = fmaf((wL), uL, ta); tb = fmaf((wL), fabsf(uL), tb);          \
    ta = fmaf((wH), uH, ta); tb = fmaf((wH), fabsf(uH), tb);          \
  }

#define COMPUTE_A(S, ST)                                              \
  {                                                                   \
    float ta = 0.f, tb = 0.f;                                         \
    UNPK(qa[S].x, ai0.x, ai0.y, wa0.x, wa0.y);                        \
    UNPK(qa[S].y, ai0.z, ai0.w, wa0.z, wa0.w);                        \
    UNPK(qa[S].z, ai1.x, ai1.y, wa1.x, wa1.y);                        \
    UNPK(qa[S].w, ai1.z, ai1.w, wa1.z, wa1.w);                        \
    float t = fmaf(0.6f, ta, 0.4f * tb);                              \
    t += __shfl_xor(t, 1);                                            \
    t += __shfl_xor(t, 2);                                            \
    t += __shfl_xor(t, 4);                                            \
    t += __shfl_xor(t, 8);                                            \
    const int edge = base + ((ST) << 2) + g;                          \
    const float p = (edge < e1) ? __expf(t) : 0.f;                    \
    pacc += (f == 0) ? p : 0.f;                                       \
    if (f == 0 && edge < e1) p_out[edge] = p;                         \
  }

  for (int base = e0; base < e1; base += 64) {
    int myidx = (base + lane < e1) ? sorted_send[base + lane] : 0;
    const int rem = e1 - base;
    const int nst = ((rem < 64 ? rem : 64) + 3) >> 2;

    if (nst > 0) ISSUE_A(0, 0);
    if (nst > 1) ISSUE_A(1, 1);
    if (nst > 2) ISSUE_A(2, 2);
    if (nst > 3) ISSUE_A(3, 3);

    int st = 0;
    for (; st + 4 <= nst; st += 4) {
      COMPUTE_A(0, st);
      if (st + 4 < nst) ISSUE_A(0, st + 4);
      COMPUTE_A(1, st + 1);
      if (st + 5 < nst) ISSUE_A(1, st + 5);
      COMPUTE_A(2, st + 2);
      if (st + 6 < nst) ISSUE_A(2, st + 6);
      COMPUTE_A(3, st + 3);
      if (st + 7 < nst) ISSUE_A(3, st + 7);
    }
    if (st < nst) COMPUTE_A(0, st);
    if (st + 1 < nst) COMPUTE_A(1, st + 1);
    if (st + 2 < nst) COMPUTE_A(2, st + 2);
  }
#undef ISSUE_A
#undef UNPK
#undef COMPUTE_A

  pacc += __shfl_xor(pacc, 16);
  pacc += __shfl_xor(pacc, 32);
  if (lane == 0) inv_denom[node] = 1.f / fmaxf(pacc, 1e-12f);
}

// ---------------- Pass B: aggregate p*WN, normalize, elu -------------------
__global__ __launch_bounds__(256) void agg_node(
    const unsigned short* __restrict__ P,
    const int* __restrict__ row_start, const int* __restrict__ sorted_send,
    const float* __restrict__ p_out, const float* __restrict__ inv_denom,
    float* __restrict__ out, int nNodes) {
  const int node = blockIdx.x * 4 + (threadIdx.x >> 6);
  const int lane = threadIdx.x & 63;
  if (node >= nNodes) return;
  const int g = lane >> 4;
  const int f = lane & 15;
  const size_t no = (size_t)node * F;

  const char* Pb = (const char*)P + 256 + (f << 4);  // WN half + f*16 bytes

  float acc[8] = {0.f, 0.f, 0.f, 0.f, 0.f, 0.f, 0.f, 0.f};
  const int e0 = row_start[node], e1 = row_start[node + 1];
  uint4 wb[4];

#define ISSUE_B(S, ST)                                                \
  {                                                                   \
    int srow = __shfl(myidx, ((ST) << 2) + g);                        \
    wb[S] = *(const uint4*)(Pb + (size_t)srow * 512);                 \
  }

#define PHB(w, k0, k1)                                                \
  {                                                                   \
    float xl = __uint_as_float((w) << 16);                            \
    float xh = __uint_as_float((w) & 0xffff0000u);                    \
    acc[k0] = fmaf(xl, pq, acc[k0]);                                  \
    acc[k1] = fmaf(xh, pq, acc[k1]);                                  \
  }

#define COMPUTE_B(S, ST)                                              \
  {                                                                   \
    const float pq = __shfl(pl, ((ST) << 2) + g);                     \
    PHB(wb[S].x, 0, 1);                                               \
    PHB(wb[S].y, 2, 3);                                               \
    PHB(wb[S].z, 4, 5);                                               \
    PHB(wb[S].w, 6, 7);                                               \
  }

  for (int base = e0; base < e1; base += 64) {
    int myidx = (base + lane < e1) ? sorted_send[base + lane] : 0;
    float pl = (base + lane < e1) ? p_out[base + lane] : 0.f;
    const int rem = e1 - base;
    const int nst = ((rem < 64 ? rem : 64) + 3) >> 2;

    if (nst > 0) ISSUE_B(0, 0);
    if (nst > 1) ISSUE_B(1, 1);
    if (nst > 2) ISSUE_B(2, 2);
    if (nst > 3) ISSUE_B(3, 3);

    int st = 0;
    for (; st + 4 <= nst; st += 4) {
      COMPUTE_B(0, st);
      if (st + 4 < nst) ISSUE_B(0, st + 4);
      COMPUTE_B(1, st + 1);
      if (st + 5 < nst) ISSUE_B(1, st + 5);
      COMPUTE_B(2, st + 2);
      if (st + 6 < nst) ISSUE_B(2, st + 6);
      COMPUTE_B(3, st + 3);
      if (st + 7 < nst) ISSUE_B(3, st + 7);
    }
    if (st < nst) COMPUTE_B(0, st);
    if (st + 1 < nst) COMPUTE_B(1, st + 1);
    if (st + 2 < nst) COMPUTE_B(2, st + 2);
  }
#undef ISSUE_B
#undef PHB
#undef COMPUTE_B

#pragma unroll
  for (int k = 0; k < 8; ++k) {
    acc[k] += __shfl_xor(acc[k], 16);
    acc[k] += __shfl_xor(acc[k], 32);
  }

  const float invd = inv_denom[node];
  if (lane < 16) {
    float o[8];
#pragma unroll
    for (int k = 0; k < 8; ++k) {
      float v = acc[k] * invd;
      o[k] = (v > 0.f) ? v : expm1f(v);
    }
    *(float4*)&out[no + (f << 3)]     = float4{o[0], o[1], o[2], o[3]};
    *(float4*)&out[no + (f << 3) + 4] = float4{o[4], o[5], o[6], o[7]};
  }
}

extern "C" void kernel_launch(void* const* d_in, const int* in_sizes, int n_in,
                              void* d_out, int out_size, void* d_ws, size_t ws_size,
                              hipStream_t stream) {
  const float* node    = (const float*)d_in[0];
  // d_in[1] = edge features: UNUSED by the reference
  const int*   ei      = (const int*)d_in[2];
  const float* W_lin   = (const float*)d_in[3];
  const float* b_lin   = (const float*)d_in[4];
  const float* W_att   = (const float*)d_in[5];
  const float* b_att   = (const float*)d_in[6];
  const float* w_alpha = (const float*)d_in[7];

  const int nNodes = in_sizes[0] / F;
  const int nEdges = in_sizes[2] / 2;

  float* ws = (float*)d_ws;
  const size_t nf = (size_t)nNodes * F;
  float*          A_in = ws;                          // nf f32
  unsigned short* P    = (unsigned short*)(ws + nf);  // nNodes*256 bf16
  int* ibase       = (int*)(ws + 2 * nf);
  int* deg         = ibase;                        // nNodes
  int* row_start   = ibase + nNodes;               // nNodes + 1
  int* bsum        = ibase + 2 * nNodes + 1;       // 256
  int* fill        = ibase + 2 * nNodes + 257;     // nNodes
  int* sorted_send = ibase + 3 * nNodes + 257;     // nEdges
  float* p_out     = (float*)(sorted_send + nEdges);  // nEdges
  float* inv_denom = p_out + nEdges;                  // nNodes

  const int nScanBlocks = (nNodes + 1023) / 1024;
  const int SB = (nEdges + 255) / 256;
  const int GB = (nNodes + 31) / 32;
  const int NB = (nNodes + 3) / 4;

  zero_kernel<<<(nNodes + 255) / 256, 256, 0, stream>>>(deg, nNodes);
  degree_kernel<<<SB, 256, 0, stream>>>((const int2*)ei, deg, nEdges);
  scan_a<<<nScanBlocks, 256, 0, stream>>>(deg, row_start, bsum, nNodes);
  scan_b<<<1, 64, 0, stream>>>(bsum, nScanBlocks);
  scan_c<<<(nNodes + 255) / 256, 256, 0, stream>>>(row_start, bsum, fill,
                                                   nNodes, nEdges);
  combo_kernel<<<SB + GB, 256, 0, stream>>>(
      (const int2*)ei, fill, sorted_send, nEdges, SB,
      node, W_lin, b_lin, W_att, b_att, A_in, P, nNodes);

  logits_node<<<NB, 256, 0, stream>>>(
      A_in, P, w_alpha, row_start, sorted_send, p_out, inv_denom, nNodes);
  agg_node<<<NB, 256, 0, stream>>>(
      P, row_start, sorted_send, p_out, inv_denom, (float*)d_out, nNodes);
}